// Round 9
// baseline (400.108 us; speedup 1.0000x reference)
//
#include <hip/hip_runtime.h>
#include <stdint.h>

#define NB 64
#define CINC 1024
#define HWD 784
#define MIDC 256
#define COUTC 1024
#define EMBD 64

typedef __attribute__((ext_vector_type(8))) short short8;
typedef __attribute__((ext_vector_type(4))) float f32x4;

#define GLOAD16(gp, lp)                                                     \
  __builtin_amdgcn_global_load_lds(                                         \
      (const __attribute__((address_space(1))) void*)(gp),                  \
      (__attribute__((address_space(3))) void*)(lp), 16, 0, 0)

__device__ __forceinline__ ushort f2bf(float f) {
  union { float f; uint32_t u; } v; v.f = f;
  uint32_t r = v.u + 0x7fffu + ((v.u >> 16) & 1u);
  return (ushort)(r >> 16);
}
__device__ __forceinline__ float bf2f(ushort b) {
  union { uint32_t u; float f; } v; v.u = ((uint32_t)b) << 16;
  return v.f;
}
__device__ __forceinline__ uint32_t pack2(float a, float b) {
  return (uint32_t)f2bf(a) | ((uint32_t)f2bf(b) << 16);
}

// ---------------- workspace layout (bytes) ----------------
static const size_t OFF_Y1   = 0;            // y1, later reused as y2p
static const size_t OFF_Y2   = 25690112;
static const size_t OFF_W1   = 51380224;
static const size_t OFF_W3   = 51904512;
static const size_t OFF_W2R  = 52428800;
static const size_t OFF_STAT = 53608448;     // 3072 floats
static const size_t OFF_PAR  = 53620736;     // 3072 floats
static const size_t OFF_ZB   = 58720256;     // z bf16 NCHW = 102760448 B

// ---------------- setup: gates + weight repack + stat zero ----------------
__global__ __launch_bounds__(256) void k_setup(
    const float* __restrict__ emb, const float* __restrict__ wg1,
    const float* __restrict__ bg1, const float* __restrict__ wg2,
    const float* __restrict__ bg2, float* __restrict__ out_tail,
    const float* __restrict__ w1, const float* __restrict__ w2,
    const float* __restrict__ w3, ushort* __restrict__ W1b,
    ushort* __restrict__ W2r, ushort* __restrict__ W3b,
    float* __restrict__ stat) {
  int bid = blockIdx.x;
  if (bid < 128) {
    int b = bid >> 1, which = bid & 1, n = threadIdx.x;
    const float* w = which ? wg2 : wg1;
    const float* bias = which ? bg2 : bg1;
    __shared__ float se[EMBD];
    if (n < EMBD) se[n] = emb[b * EMBD + n];
    __syncthreads();
    float acc = bias[n];
#pragma unroll 8
    for (int e = 0; e < EMBD; e++) acc += se[e] * w[e * MIDC + n];
    out_tail[which * (NB * MIDC) + b * MIDC + n] = fmaxf(acc, 0.f);
  } else {
    int rb = bid - 128;
    int j0 = rb * 256 + threadIdx.x;
    if (j0 < 3072) stat[j0] = 0.f;
    int total = 262144 + 262144 + 589824;
    for (int i = j0; i < total; i += 2048 * 256) {
      if (i < 262144) W1b[i] = f2bf(w1[i]);
      else if (i < 524288) W3b[i - 262144] = f2bf(w3[i - 262144]);
      else {
        int j = i - 524288;               // tap*65536 + n*256 + c
        int tap = j >> 16, n = (j >> 8) & 255, c = j & 255;
        W2r[j] = f2bf(w2[(n * 256 + c) * 9 + tap]);
      }
    }
  }
}

// ---------------- x (NCHW f32) -> xcl [m][c] bf16 ----------------
__global__ __launch_bounds__(256) void k_xpose(const float* __restrict__ x,
                                               ushort* __restrict__ xcl) {
  int mt = blockIdx.x, ct = blockIdx.y, b = blockIdx.z;
  __shared__ float tile[64][68];
  int t = threadIdx.x;
  int m0 = mt * 64, c0 = ct * 64;
  {
    int cc = t >> 2, mc = (t & 3) << 4;
    if (m0 + mc < HWD) {
      const float* src = x + ((size_t)b * CINC + c0 + cc) * HWD + m0 + mc;
#pragma unroll
      for (int e = 0; e < 4; e++) {
        float4 q = ((const float4*)src)[e];
        int mm = mc + e * 4;
        tile[mm][cc] = q.x; tile[mm + 1][cc] = q.y;
        tile[mm + 2][cc] = q.z; tile[mm + 3][cc] = q.w;
      }
    }
  }
  __syncthreads();
  {
    int m = t >> 2, cc = (t & 3) << 4;
    int mi = m0 + m;
    if (mi < HWD) {
      float* row = tile[m];
      uint32_t w[8];
#pragma unroll
      for (int e = 0; e < 8; e++) w[e] = pack2(row[cc + 2 * e], row[cc + 2 * e + 1]);
      uint4 p0, p1;
      p0.x = w[0]; p0.y = w[1]; p0.z = w[2]; p0.w = w[3];
      p1.x = w[4]; p1.y = w[5]; p1.z = w[6]; p1.w = w[7];
      uint4* dst = (uint4*)(xcl + ((size_t)b * HWD + mi) * CINC + c0 + cc);
      dst[0] = p0; dst[1] = p1;
    }
  }
}

// ---------------- conv1 1x1: 512thr, BM=128 x BN=256 x K=1024 --------------
__global__ __launch_bounds__(512, 4) void k_conv1(
    const ushort* __restrict__ xcl, const ushort* __restrict__ W1b,
    const float* __restrict__ g1, ushort* __restrict__ y1,
    float* __restrict__ sum1, float* __restrict__ sq1) {
  int mt = (blockIdx.x & 7) * 49 + (blockIdx.x >> 3);   // 392 = 8*49
  int tid = threadIdx.x, lane = tid & 63, wid = tid >> 6;  // 8 waves 2x4
  int wm = wid >> 2, wn = wid & 3;
  int lr = lane & 15, lq = lane >> 4;
  __shared__ char smem[49152];
  char* Ab = smem;            // 128 rows x 128B = 16KB
  char* Bb = smem + 16384;    // 256 rows x 128B = 32KB

  int l8 = lane >> 3, kgl = lane & 7;
  int xorg = (kgl ^ l8) * 8;
  const ushort* srcA[2]; const ushort* srcB[4];
#pragma unroll
  for (int q = 0; q < 2; q++) {
    int r = (wid * 2 + q) * 8 + l8;          // 0..127
    srcA[q] = xcl + (size_t)(mt * 128 + r) * CINC + xorg;
  }
#pragma unroll
  for (int q = 0; q < 4; q++) {
    int r = (wid * 4 + q) * 8 + l8;          // 0..255
    srcB[q] = W1b + (size_t)r * CINC + xorg;
  }
  f32x4 acc[4][4] = {};

  for (int kt = 0; kt < 16; kt++) {
    int d = kt * 64;
#pragma unroll
    for (int q = 0; q < 2; q++) GLOAD16(srcA[q] + d, Ab + (wid * 2 + q) * 1024);
#pragma unroll
    for (int q = 0; q < 4; q++) GLOAD16(srcB[q] + d, Bb + (wid * 4 + q) * 1024);
    __syncthreads();
#pragma unroll
    for (int kk = 0; kk < 2; kk++) {
      int kg = kk * 4 + lq;
      short8 af[4], bf[4];
#pragma unroll
      for (int i = 0; i < 4; i++) {
        int row = wm * 64 + i * 16 + lr;
        af[i] = *(const short8*)(Ab + row * 128 + ((kg ^ (row & 7)) << 4));
      }
#pragma unroll
      for (int j = 0; j < 4; j++) {
        int rn = wn * 64 + j * 16 + lr;
        bf[j] = *(const short8*)(Bb + rn * 128 + ((kg ^ (rn & 7)) << 4));
      }
#pragma unroll
      for (int i = 0; i < 4; i++)
#pragma unroll
        for (int j = 0; j < 4; j++)
          acc[i][j] = __builtin_amdgcn_mfma_f32_16x16x32_bf16(af[i], bf[j], acc[i][j], 0, 0, 0);
    }
    __syncthreads();
  }

  // epilogue: gate, stats, store
  int m0t = mt * 128;
  int b0 = m0t / HWD;
  int b1 = b0 + 1; if (b1 > NB - 1) b1 = NB - 1;
  int thr = (b0 + 1) * HWD;
  float gv0[4], gv1[4];
#pragma unroll
  for (int j = 0; j < 4; j++) {
    int n = wn * 64 + j * 16 + lr;
    gv0[j] = g1[b0 * MIDC + n];
    gv1[j] = g1[b1 * MIDC + n];
  }
#pragma unroll
  for (int i = 0; i < 4; i++) {
    int mlb = m0t + wm * 64 + i * 16 + lq * 4;
#pragma unroll
    for (int j = 0; j < 4; j++)
#pragma unroll
      for (int r = 0; r < 4; r++)
        acc[i][j][r] *= ((mlb + r) < thr) ? gv0[j] : gv1[j];
  }
#pragma unroll
  for (int j = 0; j < 4; j++) {
    float s = 0.f, q = 0.f;
#pragma unroll
    for (int i = 0; i < 4; i++)
#pragma unroll
      for (int r = 0; r < 4; r++) { float v = acc[i][j][r]; s += v; q += v * v; }
    s += __shfl_xor(s, 16); s += __shfl_xor(s, 32);
    q += __shfl_xor(q, 16); q += __shfl_xor(q, 32);
    if (lane < 16) {
      int n = wn * 64 + j * 16 + lane;
      atomicAdd(&sum1[n], s); atomicAdd(&sq1[n], q);
    }
  }
#pragma unroll
  for (int i = 0; i < 4; i++)
#pragma unroll
    for (int r = 0; r < 4; r++) {
      int m = m0t + wm * 64 + i * 16 + lq * 4 + r;
      ushort* dst = y1 + (size_t)m * MIDC + wn * 64 + lr;
#pragma unroll
      for (int j = 0; j < 4; j++) dst[j * 16] = f2bf(acc[i][j][r]);
    }
}

// ---------------- BN param ----------------
__global__ void k_bnpar(const float* __restrict__ st, const float* __restrict__ gamma,
                        const float* __restrict__ beta, float* __restrict__ so,
                        float* __restrict__ to, int C) {
  int c = blockIdx.x * blockDim.x + threadIdx.x;
  if (c >= C) return;
  const float cnt = 50176.f;
  float m = st[c] / cnt;
  float v = st[C + c] / cnt - m * m;
  float s = gamma[c] * rsqrtf(v + 1e-5f);
  so[c] = s; to[c] = beta[c] - m * s;
}

// ---------------- bn1+relu prepass: y1 -> y1p padded [64][30][30][256] ------
__global__ __launch_bounds__(256) void k_bnrelu(
    const ushort* __restrict__ y1, const float* __restrict__ s1,
    const float* __restrict__ t1, ushort* __restrict__ y1p) {
  __shared__ float sS[MIDC], sT[MIDC];
  int t = threadIdx.x;
  sS[t] = s1[t]; sT[t] = t1[t];
  __syncthreads();
  int pl = t >> 5, ch = (t & 31) * 8;
  int pos = blockIdx.x * 8 + pl;          // 0..57599
  int b = pos / 900, pp = pos % 900;
  int pr = pp / 30, pc = pp % 30;
  uint4 ov = {0u, 0u, 0u, 0u};
  if (pr > 0 && pr < 29 && pc > 0 && pc < 29) {
    uint4 raw = *(const uint4*)(y1 + ((size_t)b * HWD + (pr - 1) * 28 + (pc - 1)) * MIDC + ch);
    ushort* rw = (ushort*)&raw; ushort* ow = (ushort*)&ov;
#pragma unroll
    for (int e = 0; e < 8; e++) {
      float f = bf2f(rw[e]) * sS[ch + e] + sT[ch + e];
      ow[e] = f2bf(fmaxf(f, 0.f));
    }
  }
  *(uint4*)(y1p + (size_t)pos * MIDC + ch) = ov;
}

// ---------------- bn2+relu prepass: y2 -> y2p [m][c] bf16 ------------------
__global__ __launch_bounds__(256) void k_bnrelu2(
    const ushort* __restrict__ y2, const float* __restrict__ s2,
    const float* __restrict__ t2, ushort* __restrict__ y2p) {
  __shared__ float sS[MIDC], sT[MIDC];
  int t = threadIdx.x;
  sS[t] = s2[t]; sT[t] = t2[t];
  __syncthreads();
  int pl = t >> 5, ch = (t & 31) * 8;
  size_t pos = (size_t)blockIdx.x * 8 + pl;   // 0..50175
  uint4 raw = *(const uint4*)(y2 + pos * MIDC + ch);
  uint4 ov;
  ushort* rw = (ushort*)&raw; ushort* ow = (ushort*)&ov;
#pragma unroll
  for (int e = 0; e < 8; e++) {
    float f = bf2f(rw[e]) * sS[ch + e] + sT[ch + e];
    ow[e] = f2bf(fmaxf(f, 0.f));
  }
  *(uint4*)(y2p + pos * MIDC + ch) = ov;
}

// ---------------- conv2 3x3: 512thr, BM=128 x BN=256, K=2304 ---------------
__global__ __launch_bounds__(512, 4) void k_conv2(
    const ushort* __restrict__ y1p, const ushort* __restrict__ W2r,
    const float* __restrict__ g2, ushort* __restrict__ y2,
    float* __restrict__ sum2, float* __restrict__ sq2) {
  int mt = (blockIdx.x & 7) * 49 + (blockIdx.x >> 3);   // 392 = 8*49
  int tid = threadIdx.x, lane = tid & 63, wid = tid >> 6;  // 8 waves 2x4
  int wm = wid >> 2, wn = wid & 3;
  int lr = lane & 15, lq = lane >> 4;
  __shared__ char smem[49152];
  char* Ab = smem;
  char* Bb = smem + 16384;

  int l8 = lane >> 3, kgl = lane & 7;
  int xorg = (kgl ^ l8) * 8;
  const ushort* srcA[2]; const ushort* srcB[4];
#pragma unroll
  for (int q = 0; q < 2; q++) {
    int r = (wid * 2 + q) * 8 + l8;
    int m = mt * 128 + r;
    int b = m / HWD, rem = m % HWD;
    int h = rem / 28, w = rem % 28;
    srcA[q] = y1p + ((size_t)b * 900 + (h + 1) * 30 + (w + 1)) * MIDC + xorg;
  }
#pragma unroll
  for (int q = 0; q < 4; q++) {
    int r = (wid * 4 + q) * 8 + l8;          // 0..255
    srcB[q] = W2r + (size_t)r * MIDC + xorg;
  }
  f32x4 acc[4][4] = {};

  for (int kt = 0; kt < 36; kt++) {
    int tap = kt >> 2, cq = kt & 3;
    int dy = tap / 3, dx = tap % 3;
    int dA = ((dy - 1) * 30 + (dx - 1)) * MIDC + cq * 64;
    int dB = tap * 65536 + cq * 64;
#pragma unroll
    for (int q = 0; q < 2; q++) GLOAD16(srcA[q] + dA, Ab + (wid * 2 + q) * 1024);
#pragma unroll
    for (int q = 0; q < 4; q++) GLOAD16(srcB[q] + dB, Bb + (wid * 4 + q) * 1024);
    __syncthreads();
#pragma unroll
    for (int kk = 0; kk < 2; kk++) {
      int kg = kk * 4 + lq;
      short8 af[4], bf[4];
#pragma unroll
      for (int i = 0; i < 4; i++) {
        int row = wm * 64 + i * 16 + lr;
        af[i] = *(const short8*)(Ab + row * 128 + ((kg ^ (row & 7)) << 4));
      }
#pragma unroll
      for (int j = 0; j < 4; j++) {
        int rn = wn * 64 + j * 16 + lr;
        bf[j] = *(const short8*)(Bb + rn * 128 + ((kg ^ (rn & 7)) << 4));
      }
#pragma unroll
      for (int i = 0; i < 4; i++)
#pragma unroll
        for (int j = 0; j < 4; j++)
          acc[i][j] = __builtin_amdgcn_mfma_f32_16x16x32_bf16(af[i], bf[j], acc[i][j], 0, 0, 0);
    }
    __syncthreads();
  }

  // epilogue
  int m0t = mt * 128;
  int b0 = m0t / HWD;
  int b1 = b0 + 1; if (b1 > NB - 1) b1 = NB - 1;
  int thr = (b0 + 1) * HWD;
  float gv0[4], gv1[4];
#pragma unroll
  for (int j = 0; j < 4; j++) {
    int n = wn * 64 + j * 16 + lr;
    gv0[j] = g2[b0 * MIDC + n];
    gv1[j] = g2[b1 * MIDC + n];
  }
#pragma unroll
  for (int i = 0; i < 4; i++) {
    int mlb = m0t + wm * 64 + i * 16 + lq * 4;
#pragma unroll
    for (int j = 0; j < 4; j++)
#pragma unroll
      for (int r = 0; r < 4; r++)
        acc[i][j][r] *= ((mlb + r) < thr) ? gv0[j] : gv1[j];
  }
#pragma unroll
  for (int j = 0; j < 4; j++) {
    float s = 0.f, q = 0.f;
#pragma unroll
    for (int i = 0; i < 4; i++)
#pragma unroll
      for (int r = 0; r < 4; r++) { float v = acc[i][j][r]; s += v; q += v * v; }
    s += __shfl_xor(s, 16); s += __shfl_xor(s, 32);
    q += __shfl_xor(q, 16); q += __shfl_xor(q, 32);
    if (lane < 16) {
      int n = wn * 64 + j * 16 + lane;
      atomicAdd(&sum2[n], s); atomicAdd(&sq2[n], q);
    }
  }
#pragma unroll
  for (int i = 0; i < 4; i++)
#pragma unroll
    for (int r = 0; r < 4; r++) {
      int m = m0t + wm * 64 + i * 16 + lq * 4 + r;
      ushort* dst = y2 + (size_t)m * MIDC + wn * 64 + lr;
#pragma unroll
      for (int j = 0; j < 4; j++) dst[j * 16] = f2bf(acc[i][j][r]);
    }
}

// ---------------- conv3 1x1: 512thr, BM=128 x BN=256(4 nt) x K=256 ---------
__global__ __launch_bounds__(512, 4) void k_conv3(
    const ushort* __restrict__ y2p, const ushort* __restrict__ W3b,
    ushort* __restrict__ zbn, float* __restrict__ sum3, float* __restrict__ sq3) {
  int bid = (blockIdx.x & 7) * 196 + (blockIdx.x >> 3);  // 1568 = 8*196
  int mt = bid >> 2, nt = bid & 3;
  int tid = threadIdx.x, lane = tid & 63, wid = tid >> 6;  // 8 waves 2x4
  int wm = wid >> 2, wn = wid & 3;
  int lr = lane & 15, lq = lane >> 4;
  __shared__ char smem[49152];
  char* Ab = smem;
  char* Bb = smem + 16384;

  int l8 = lane >> 3, kgl = lane & 7;
  int xorg = (kgl ^ l8) * 8;
  const ushort* srcA[2]; const ushort* srcB[4];
#pragma unroll
  for (int q = 0; q < 2; q++) {
    int r = (wid * 2 + q) * 8 + l8;
    srcA[q] = y2p + (size_t)(mt * 128 + r) * MIDC + xorg;
  }
#pragma unroll
  for (int q = 0; q < 4; q++) {
    int r = (wid * 4 + q) * 8 + l8;          // 0..255
    srcB[q] = W3b + (size_t)(nt * 256 + r) * MIDC + xorg;
  }
  f32x4 acc[4][4] = {};

  for (int kt = 0; kt < 4; kt++) {
    int d = kt * 64;
#pragma unroll
    for (int q = 0; q < 2; q++) GLOAD16(srcA[q] + d, Ab + (wid * 2 + q) * 1024);
#pragma unroll
    for (int q = 0; q < 4; q++) GLOAD16(srcB[q] + d, Bb + (wid * 4 + q) * 1024);
    __syncthreads();
#pragma unroll
    for (int kk = 0; kk < 2; kk++) {
      int kg = kk * 4 + lq;
      short8 af[4], bf[4];
#pragma unroll
      for (int i = 0; i < 4; i++) {
        int row = wm * 64 + i * 16 + lr;
        af[i] = *(const short8*)(Ab + row * 128 + ((kg ^ (row & 7)) << 4));
      }
#pragma unroll
      for (int j = 0; j < 4; j++) {
        int rn = wn * 64 + j * 16 + lr;
        bf[j] = *(const short8*)(Bb + rn * 128 + ((kg ^ (rn & 7)) << 4));
      }
#pragma unroll
      for (int i = 0; i < 4; i++)
#pragma unroll
        for (int j = 0; j < 4; j++)
          acc[i][j] = __builtin_amdgcn_mfma_f32_16x16x32_bf16(af[i], bf[j], acc[i][j], 0, 0, 0);
    }
    __syncthreads();
  }

  // stats
#pragma unroll
  for (int j = 0; j < 4; j++) {
    float s = 0.f, q = 0.f;
#pragma unroll
    for (int i = 0; i < 4; i++)
#pragma unroll
      for (int r = 0; r < 4; r++) { float v = acc[i][j][r]; s += v; q += v * v; }
    s += __shfl_xor(s, 16); s += __shfl_xor(s, 32);
    q += __shfl_xor(q, 16); q += __shfl_xor(q, 32);
    if (lane < 16) {
      int n = nt * 256 + wn * 64 + j * 16 + lane;
      atomicAdd(&sum3[n], s); atomicAdd(&sq3[n], q);
    }
  }

  // z bf16 NCHW via LDS repack; 4 phases of 64 channels (waves wn==h write)
  float* ldsf = (float*)smem;          // [64][132] f32 = 33792 B
  int m0t = mt * 128;
  for (int h = 0; h < 4; h++) {
    __syncthreads();
    if (wn == h) {
#pragma unroll
      for (int i = 0; i < 4; i++)
#pragma unroll
        for (int j = 0; j < 4; j++) {
          int nc = j * 16 + lr;
#pragma unroll
          for (int r = 0; r < 4; r++) {
            int m = wm * 64 + i * 16 + lq * 4 + r;
            ldsf[nc * 132 + m] = acc[i][j][r];
          }
        }
    }
    __syncthreads();
    int c0 = nt * 256 + h * 64;
    int l = tid & 15;
    int m = m0t + l * 8;
    int b = m / HWD, hw = m % HWD;
#pragma unroll
    for (int pass = 0; pass < 2; pass++) {
      int row = pass * 32 + (tid >> 4);
      const float* src = &ldsf[row * 132 + l * 8];
      uint4 pv;
      pv.x = pack2(src[0], src[1]); pv.y = pack2(src[2], src[3]);
      pv.z = pack2(src[4], src[5]); pv.w = pack2(src[6], src[7]);
      *(uint4*)(zbn + ((size_t)(b * COUTC + c0 + row)) * HWD + hw) = pv;
    }
  }
}

// ---------------- final: out = relu(bn3(zbn) + x), fully linear ------------
__global__ __launch_bounds__(256) void k_final(
    const ushort* __restrict__ zbn, const float* __restrict__ x,
    const float* __restrict__ s3, const float* __restrict__ t3,
    float* __restrict__ outp) {
  int stride = gridDim.x * blockDim.x;
  int total = (NB * COUTC * HWD) / 8;
  for (int i = blockIdx.x * blockDim.x + threadIdx.x; i < total; i += stride) {
    size_t e0 = (size_t)i * 8;
    int c = (int)((e0 / HWD) & (COUTC - 1));
    float s = s3[c], tt = t3[c];
    uint4 zr = *(const uint4*)(zbn + e0);
    ushort* zw = (ushort*)&zr;
    float4 x0 = *(const float4*)(x + e0);
    float4 x1 = *(const float4*)(x + e0 + 4);
    float4 o0, o1;
    o0.x = fmaxf(fmaf(bf2f(zw[0]), s, tt) + x0.x, 0.f);
    o0.y = fmaxf(fmaf(bf2f(zw[1]), s, tt) + x0.y, 0.f);
    o0.z = fmaxf(fmaf(bf2f(zw[2]), s, tt) + x0.z, 0.f);
    o0.w = fmaxf(fmaf(bf2f(zw[3]), s, tt) + x0.w, 0.f);
    o1.x = fmaxf(fmaf(bf2f(zw[4]), s, tt) + x1.x, 0.f);
    o1.y = fmaxf(fmaf(bf2f(zw[5]), s, tt) + x1.y, 0.f);
    o1.z = fmaxf(fmaf(bf2f(zw[6]), s, tt) + x1.z, 0.f);
    o1.w = fmaxf(fmaf(bf2f(zw[7]), s, tt) + x1.w, 0.f);
    *(float4*)(outp + e0) = o0;
    *(float4*)(outp + e0 + 4) = o1;
  }
}

extern "C" void kernel_launch(void* const* d_in, const int* in_sizes, int n_in,
                              void* d_out, int out_size, void* d_ws, size_t ws_size,
                              hipStream_t stream) {
  const float* x    = (const float*)d_in[0];
  const float* emb  = (const float*)d_in[1];
  const float* wg1  = (const float*)d_in[2];
  const float* bg1  = (const float*)d_in[3];
  const float* wg2  = (const float*)d_in[4];
  const float* bg2  = (const float*)d_in[5];
  const float* c1w  = (const float*)d_in[6];
  const float* bn1g = (const float*)d_in[7];
  const float* bn1b = (const float*)d_in[8];
  const float* c2w  = (const float*)d_in[9];
  const float* bn2g = (const float*)d_in[10];
  const float* bn2b = (const float*)d_in[11];
  const float* c3w  = (const float*)d_in[12];
  const float* bn3g = (const float*)d_in[13];
  const float* bn3b = (const float*)d_in[14];

  float* out = (float*)d_out;
  char* ws = (char*)d_ws;
  ushort* y1  = (ushort*)(ws + OFF_Y1);
  ushort* y2p = (ushort*)(ws + OFF_Y1);   // reuses y1 region
  ushort* y2  = (ushort*)(ws + OFF_Y2);
  ushort* W1b = (ushort*)(ws + OFF_W1);
  ushort* W3b = (ushort*)(ws + OFF_W3);
  ushort* W2r = (ushort*)(ws + OFF_W2R);
  float* stat = (float*)(ws + OFF_STAT);
  float* par  = (float*)(ws + OFF_PAR);
  ushort* zbn = (ushort*)(ws + OFF_ZB);

  float* sum1 = stat;        float* sq1 = stat + 256;
  float* sum2 = stat + 512;  float* sq2 = stat + 768;
  float* sum3 = stat + 1024; float* sq3 = stat + 2048;
  float* s1 = par;        float* t1 = par + 256;
  float* s2 = par + 512;  float* t2 = par + 768;
  float* s3 = par + 1024; float* t3 = par + 2048;

  ushort* xcl = (ushort*)out;
  ushort* y1p = (ushort*)(out + 25690112);
  float* out_tail = out + 51380224;

  k_setup<<<2176, 256, 0, stream>>>(emb, wg1, bg1, wg2, bg2, out_tail,
                                    c1w, c2w, c3w, W1b, W2r, W3b, stat);
  k_xpose<<<dim3(13, 16, 64), 256, 0, stream>>>(x, xcl);
  k_conv1<<<392, 512, 0, stream>>>(xcl, W1b, out_tail, y1, sum1, sq1);
  k_bnpar<<<1, 256, 0, stream>>>(stat, bn1g, bn1b, s1, t1, 256);
  k_bnrelu<<<7200, 256, 0, stream>>>(y1, s1, t1, y1p);
  k_conv2<<<392, 512, 0, stream>>>(y1p, W2r, out_tail + 16384, y2, sum2, sq2);
  k_bnpar<<<1, 256, 0, stream>>>(stat + 512, bn2g, bn2b, s2, t2, 256);
  k_bnrelu2<<<6272, 256, 0, stream>>>(y2, s2, t2, y2p);
  k_conv3<<<1568, 512, 0, stream>>>(y2p, W3b, zbn, sum3, sq3);
  k_bnpar<<<4, 256, 0, stream>>>(stat + 1024, bn3g, bn3b, s3, t3, 1024);
  k_final<<<2048, 256, 0, stream>>>(zbn, x, s3, t3, out);
}

// Round 10
// 389.204 us; speedup vs baseline: 1.0280x; 1.0280x over previous
//
#include <hip/hip_runtime.h>
#include <stdint.h>

#define NB 64
#define CINC 1024
#define HWD 784
#define MIDC 256
#define COUTC 1024
#define EMBD 64

typedef __attribute__((ext_vector_type(8))) short short8;
typedef __attribute__((ext_vector_type(4))) float f32x4;

#define GLOAD16(gp, lp)                                                     \
  __builtin_amdgcn_global_load_lds(                                         \
      (const __attribute__((address_space(1))) void*)(gp),                  \
      (__attribute__((address_space(3))) void*)(lp), 16, 0, 0)

__device__ __forceinline__ ushort f2bf(float f) {
  union { float f; uint32_t u; } v; v.f = f;
  uint32_t r = v.u + 0x7fffu + ((v.u >> 16) & 1u);
  return (ushort)(r >> 16);
}
__device__ __forceinline__ float bf2f(ushort b) {
  union { uint32_t u; float f; } v; v.u = ((uint32_t)b) << 16;
  return v.f;
}
__device__ __forceinline__ uint32_t pack2(float a, float b) {
  return (uint32_t)f2bf(a) | ((uint32_t)f2bf(b) << 16);
}

// ---------------- workspace layout (bytes) ----------------
// ws_size = 4 x out_bytes ~ 822 MB (verified: poison fill = 803328 KB)
static const size_t OFF_Y1   = 0;            // y1, later reused as y2p
static const size_t OFF_Y2   = 25690112;
static const size_t OFF_W1   = 51380224;
static const size_t OFF_W3   = 51904512;
static const size_t OFF_W2R  = 52428800;
static const size_t OFF_STAT = 53608448;     // 3072 floats
static const size_t OFF_PAR  = 53620736;     // 3072 floats
static const size_t OFF_ZB   = 58720256;     // z bf16 NCHW [64][1024][784] = 102760448 B

// ---------------- gates ----------------
__global__ __launch_bounds__(256) void k_gates(
    const float* __restrict__ emb, const float* __restrict__ w1,
    const float* __restrict__ b1, const float* __restrict__ w2,
    const float* __restrict__ b2, float* __restrict__ out_tail) {
  int b = blockIdx.x, which = blockIdx.y, n = threadIdx.x;
  const float* w = which ? w2 : w1;
  const float* bias = which ? b2 : b1;
  __shared__ float se[EMBD];
  if (n < EMBD) se[n] = emb[b * EMBD + n];
  __syncthreads();
  float acc = bias[n];
#pragma unroll 8
  for (int e = 0; e < EMBD; e++) acc += se[e] * w[e * MIDC + n];
  acc = fmaxf(acc, 0.f);
  out_tail[which * (NB * MIDC) + b * MIDC + n] = acc;
}

// ---------------- weight repack ----------------
__global__ void k_repack(const float* __restrict__ w1, const float* __restrict__ w2,
                         const float* __restrict__ w3, ushort* __restrict__ W1b,
                         ushort* __restrict__ W2r, ushort* __restrict__ W3b) {
  int total = 262144 + 262144 + 589824;
  for (int i = blockIdx.x * blockDim.x + threadIdx.x; i < total;
       i += gridDim.x * blockDim.x) {
    if (i < 262144) W1b[i] = f2bf(w1[i]);
    else if (i < 524288) W3b[i - 262144] = f2bf(w3[i - 262144]);
    else {
      int j = i - 524288;                 // tap*65536 + n*256 + c
      int tap = j >> 16, n = (j >> 8) & 255, c = j & 255;
      W2r[j] = f2bf(w2[(n * 256 + c) * 9 + tap]);
    }
  }
}

// ---------------- x (NCHW f32) -> xcl [m][c] bf16 ----------------
__global__ __launch_bounds__(256) void k_xpose(const float* __restrict__ x,
                                               ushort* __restrict__ xcl) {
  int mt = blockIdx.x, ct = blockIdx.y, b = blockIdx.z;
  __shared__ float tile[64][68];
  int t = threadIdx.x;
  int m0 = mt * 64, c0 = ct * 64;
  {
    int cc = t >> 2, mc = (t & 3) << 4;
    if (m0 + mc < HWD) {
      const float* src = x + ((size_t)b * CINC + c0 + cc) * HWD + m0 + mc;
#pragma unroll
      for (int e = 0; e < 4; e++) {
        float4 q = ((const float4*)src)[e];
        int mm = mc + e * 4;
        tile[mm][cc] = q.x; tile[mm + 1][cc] = q.y;
        tile[mm + 2][cc] = q.z; tile[mm + 3][cc] = q.w;
      }
    }
  }
  __syncthreads();
  {
    int m = t >> 2, cc = (t & 3) << 4;
    int mi = m0 + m;
    if (mi < HWD) {
      float* row = tile[m];
      uint32_t w[8];
#pragma unroll
      for (int e = 0; e < 8; e++) w[e] = pack2(row[cc + 2 * e], row[cc + 2 * e + 1]);
      uint4 p0, p1;
      p0.x = w[0]; p0.y = w[1]; p0.z = w[2]; p0.w = w[3];
      p1.x = w[4]; p1.y = w[5]; p1.z = w[6]; p1.w = w[7];
      uint4* dst = (uint4*)(xcl + ((size_t)b * HWD + mi) * CINC + c0 + cc);
      dst[0] = p0; dst[1] = p1;
    }
  }
}

// ---------------- conv1 1x1 (m97-style): M=50176 x N=256(2 nt) x K=1024 ----
__global__ __launch_bounds__(256, 3) void k_conv1(
    const ushort* __restrict__ xcl, const ushort* __restrict__ W1b,
    const float* __restrict__ g1, ushort* __restrict__ y1,
    float* __restrict__ sum1, float* __restrict__ sq1) {
  int bid = (blockIdx.x & 7) * 98 + (blockIdx.x >> 3);   // XCD chunked swizzle
  int mt = bid >> 1, nt = bid & 1;
  int tid = threadIdx.x, lane = tid & 63, wid = tid >> 6;  // 4 waves 2x2
  int wm = wid >> 1, wn = wid & 1;
  int lr = lane & 15, lq = lane >> 4;
  __shared__ char smem[32768];
  char* Ab = smem;            // 128 rows x 128B
  char* Bb = smem + 16384;    // 128 rows x 128B

  int l8 = lane >> 3, kgl = lane & 7;
  int xorg = (kgl ^ l8) * 8;  // element offset of swizzled granule
  const ushort* srcA[4]; const ushort* srcB[4];
#pragma unroll
  for (int q = 0; q < 4; q++) {
    int r = (wid * 4 + q) * 8 + l8;
    int m = mt * 128 + r;
    srcA[q] = xcl + (size_t)m * CINC + xorg;
    int n = nt * 128 + r;
    srcB[q] = W1b + (size_t)n * CINC + xorg;
  }
  f32x4 acc[4][4] = {};

  for (int kt = 0; kt < 16; kt++) {
    int d = kt * 64;
#pragma unroll
    for (int q = 0; q < 4; q++) GLOAD16(srcA[q] + d, Ab + (wid * 4 + q) * 1024);
#pragma unroll
    for (int q = 0; q < 4; q++) GLOAD16(srcB[q] + d, Bb + (wid * 4 + q) * 1024);
    __syncthreads();
#pragma unroll
    for (int kk = 0; kk < 2; kk++) {
      int kg = kk * 4 + lq;
      short8 af[4], bf[4];
#pragma unroll
      for (int i = 0; i < 4; i++) {
        int row = wm * 64 + i * 16 + lr;
        af[i] = *(const short8*)(Ab + row * 128 + ((kg ^ (row & 7)) << 4));
      }
#pragma unroll
      for (int j = 0; j < 4; j++) {
        int rn = wn * 64 + j * 16 + lr;
        bf[j] = *(const short8*)(Bb + rn * 128 + ((kg ^ (rn & 7)) << 4));
      }
#pragma unroll
      for (int i = 0; i < 4; i++)
#pragma unroll
        for (int j = 0; j < 4; j++)
          acc[i][j] = __builtin_amdgcn_mfma_f32_16x16x32_bf16(af[i], bf[j], acc[i][j], 0, 0, 0);
    }
    __syncthreads();
  }

  // epilogue: gate (b = m/784, at most 2 distinct b per tile), stats, store
  int m0t = mt * 128;
  int b0 = m0t / HWD;
  int b1 = b0 + 1; if (b1 > NB - 1) b1 = NB - 1;
  int thr = (b0 + 1) * HWD;
  float gv0[4], gv1[4];
#pragma unroll
  for (int j = 0; j < 4; j++) {
    int n = nt * 128 + wn * 64 + j * 16 + lr;
    gv0[j] = g1[b0 * MIDC + n];
    gv1[j] = g1[b1 * MIDC + n];
  }
#pragma unroll
  for (int i = 0; i < 4; i++) {
    int mlb = m0t + wm * 64 + i * 16 + lq * 4;
#pragma unroll
    for (int j = 0; j < 4; j++)
#pragma unroll
      for (int r = 0; r < 4; r++)
        acc[i][j][r] *= ((mlb + r) < thr) ? gv0[j] : gv1[j];
  }
#pragma unroll
  for (int j = 0; j < 4; j++) {
    float s = 0.f, q = 0.f;
#pragma unroll
    for (int i = 0; i < 4; i++)
#pragma unroll
      for (int r = 0; r < 4; r++) { float v = acc[i][j][r]; s += v; q += v * v; }
    s += __shfl_xor(s, 16); s += __shfl_xor(s, 32);
    q += __shfl_xor(q, 16); q += __shfl_xor(q, 32);
    if (lane < 16) {
      int n = nt * 128 + wn * 64 + j * 16 + lane;
      atomicAdd(&sum1[n], s); atomicAdd(&sq1[n], q);
    }
  }
#pragma unroll
  for (int i = 0; i < 4; i++)
#pragma unroll
    for (int r = 0; r < 4; r++) {
      int m = m0t + wm * 64 + i * 16 + lq * 4 + r;
      ushort* dst = y1 + (size_t)m * MIDC + nt * 128 + wn * 64 + lr;
#pragma unroll
      for (int j = 0; j < 4; j++) dst[j * 16] = f2bf(acc[i][j][r]);
    }
}

// ---------------- BN param ----------------
__global__ void k_bnpar(const float* __restrict__ st, const float* __restrict__ gamma,
                        const float* __restrict__ beta, float* __restrict__ so,
                        float* __restrict__ to, int C) {
  int c = blockIdx.x * blockDim.x + threadIdx.x;
  if (c >= C) return;
  const float cnt = 50176.f;
  float m = st[c] / cnt;
  float v = st[C + c] / cnt - m * m;
  float s = gamma[c] * rsqrtf(v + 1e-5f);
  so[c] = s; to[c] = beta[c] - m * s;
}

// ---------------- bn1+relu prepass: y1 -> y1p padded [64][30][30][256] ------
__global__ __launch_bounds__(256) void k_bnrelu(
    const ushort* __restrict__ y1, const float* __restrict__ s1,
    const float* __restrict__ t1, ushort* __restrict__ y1p) {
  __shared__ float sS[MIDC], sT[MIDC];
  int t = threadIdx.x;
  sS[t] = s1[t]; sT[t] = t1[t];
  __syncthreads();
  int pl = t >> 5, ch = (t & 31) * 8;
  int pos = blockIdx.x * 8 + pl;          // 0..57599
  int b = pos / 900, pp = pos % 900;
  int pr = pp / 30, pc = pp % 30;
  uint4 ov = {0u, 0u, 0u, 0u};
  if (pr > 0 && pr < 29 && pc > 0 && pc < 29) {
    uint4 raw = *(const uint4*)(y1 + ((size_t)b * HWD + (pr - 1) * 28 + (pc - 1)) * MIDC + ch);
    ushort* rw = (ushort*)&raw; ushort* ow = (ushort*)&ov;
#pragma unroll
    for (int e = 0; e < 8; e++) {
      float f = bf2f(rw[e]) * sS[ch + e] + sT[ch + e];
      ow[e] = f2bf(fmaxf(f, 0.f));
    }
  }
  *(uint4*)(y1p + (size_t)pos * MIDC + ch) = ov;
}

// ---------------- bn2+relu prepass: y2 -> y2p [m][c] bf16 (no padding) ------
__global__ __launch_bounds__(256) void k_bnrelu2(
    const ushort* __restrict__ y2, const float* __restrict__ s2,
    const float* __restrict__ t2, ushort* __restrict__ y2p) {
  __shared__ float sS[MIDC], sT[MIDC];
  int t = threadIdx.x;
  sS[t] = s2[t]; sT[t] = t2[t];
  __syncthreads();
  int pl = t >> 5, ch = (t & 31) * 8;
  size_t pos = (size_t)blockIdx.x * 8 + pl;   // 0..50175
  uint4 raw = *(const uint4*)(y2 + pos * MIDC + ch);
  uint4 ov;
  ushort* rw = (ushort*)&raw; ushort* ow = (ushort*)&ov;
#pragma unroll
  for (int e = 0; e < 8; e++) {
    float f = bf2f(rw[e]) * sS[ch + e] + sT[ch + e];
    ow[e] = f2bf(fmaxf(f, 0.f));
  }
  *(uint4*)(y2p + pos * MIDC + ch) = ov;
}

// ---------------- conv2 3x3 (m97-style implicit GEMM over padded y1p) -------
// M=50176 x N=256(2 nt) x K=2304 (9 taps x 4 quarters of 64ch)
__global__ __launch_bounds__(256, 3) void k_conv2(
    const ushort* __restrict__ y1p, const ushort* __restrict__ W2r,
    const float* __restrict__ g2, ushort* __restrict__ y2,
    float* __restrict__ sum2, float* __restrict__ sq2) {
  int bid = (blockIdx.x & 7) * 98 + (blockIdx.x >> 3);   // XCD chunked swizzle
  int mt = bid >> 1, nt = bid & 1;
  int tid = threadIdx.x, lane = tid & 63, wid = tid >> 6;  // 4 waves 2x2
  int wm = wid >> 1, wn = wid & 1;
  int lr = lane & 15, lq = lane >> 4;
  __shared__ char smem[32768];
  char* Ab = smem;            // 128 rows x 128B
  char* Bb = smem + 16384;    // 128 rows x 128B

  int l8 = lane >> 3, kgl = lane & 7;
  int xorg = (kgl ^ l8) * 8;
  const ushort* srcA[4]; const ushort* srcB[4];
#pragma unroll
  for (int q = 0; q < 4; q++) {
    int r = (wid * 4 + q) * 8 + l8;
    int m = mt * 128 + r;
    int b = m / HWD, rem = m % HWD;
    int h = rem / 28, w = rem % 28;
    srcA[q] = y1p + ((size_t)b * 900 + (h + 1) * 30 + (w + 1)) * MIDC + xorg;
    int n = nt * 128 + r;
    srcB[q] = W2r + (size_t)n * MIDC + xorg;
  }
  f32x4 acc[4][4] = {};

  for (int kt = 0; kt < 36; kt++) {
    int tap = kt >> 2, cq = kt & 3;
    int dy = tap / 3, dx = tap % 3;
    int dA = ((dy - 1) * 30 + (dx - 1)) * MIDC + cq * 64;
    int dB = tap * 65536 + cq * 64;
#pragma unroll
    for (int q = 0; q < 4; q++) GLOAD16(srcA[q] + dA, Ab + (wid * 4 + q) * 1024);
#pragma unroll
    for (int q = 0; q < 4; q++) GLOAD16(srcB[q] + dB, Bb + (wid * 4 + q) * 1024);
    __syncthreads();
#pragma unroll
    for (int kk = 0; kk < 2; kk++) {
      int kg = kk * 4 + lq;
      short8 af[4], bf[4];
#pragma unroll
      for (int i = 0; i < 4; i++) {
        int row = wm * 64 + i * 16 + lr;
        af[i] = *(const short8*)(Ab + row * 128 + ((kg ^ (row & 7)) << 4));
      }
#pragma unroll
      for (int j = 0; j < 4; j++) {
        int rn = wn * 64 + j * 16 + lr;
        bf[j] = *(const short8*)(Bb + rn * 128 + ((kg ^ (rn & 7)) << 4));
      }
#pragma unroll
      for (int i = 0; i < 4; i++)
#pragma unroll
        for (int j = 0; j < 4; j++)
          acc[i][j] = __builtin_amdgcn_mfma_f32_16x16x32_bf16(af[i], bf[j], acc[i][j], 0, 0, 0);
    }
    __syncthreads();
  }

  // epilogue
  int m0t = mt * 128;
  int b0 = m0t / HWD;
  int b1 = b0 + 1; if (b1 > NB - 1) b1 = NB - 1;
  int thr = (b0 + 1) * HWD;
  float gv0[4], gv1[4];
#pragma unroll
  for (int j = 0; j < 4; j++) {
    int n = nt * 128 + wn * 64 + j * 16 + lr;
    gv0[j] = g2[b0 * MIDC + n];
    gv1[j] = g2[b1 * MIDC + n];
  }
#pragma unroll
  for (int i = 0; i < 4; i++) {
    int mlb = m0t + wm * 64 + i * 16 + lq * 4;
#pragma unroll
    for (int j = 0; j < 4; j++)
#pragma unroll
      for (int r = 0; r < 4; r++)
        acc[i][j][r] *= ((mlb + r) < thr) ? gv0[j] : gv1[j];
  }
#pragma unroll
  for (int j = 0; j < 4; j++) {
    float s = 0.f, q = 0.f;
#pragma unroll
    for (int i = 0; i < 4; i++)
#pragma unroll
      for (int r = 0; r < 4; r++) { float v = acc[i][j][r]; s += v; q += v * v; }
    s += __shfl_xor(s, 16); s += __shfl_xor(s, 32);
    q += __shfl_xor(q, 16); q += __shfl_xor(q, 32);
    if (lane < 16) {
      int n = nt * 128 + wn * 64 + j * 16 + lane;
      atomicAdd(&sum2[n], s); atomicAdd(&sq2[n], q);
    }
  }
#pragma unroll
  for (int i = 0; i < 4; i++)
#pragma unroll
    for (int r = 0; r < 4; r++) {
      int m = m0t + wm * 64 + i * 16 + lq * 4 + r;
      ushort* dst = y2 + (size_t)m * MIDC + nt * 128 + wn * 64 + lr;
#pragma unroll
      for (int j = 0; j < 4; j++) dst[j * 16] = f2bf(acc[i][j][r]);
    }
}

// ---------------- conv3 1x1 (m97-style): M=50176 x N=1024(8 nt) x K=256 -----
// A = y2p (bn2+relu pre-applied). z stored bf16 NCHW via LDS repack with
// full-line contiguous copy-out (16 lanes x 16B = 256B per row-segment).
__global__ __launch_bounds__(256, 3) void k_conv3(
    const ushort* __restrict__ y2p, const ushort* __restrict__ W3b,
    ushort* __restrict__ zbn, float* __restrict__ sum3, float* __restrict__ sq3) {
  int bid = (blockIdx.x & 7) * 392 + (blockIdx.x >> 3);  // XCD chunked swizzle
  int mt = bid >> 3, nt = bid & 7;
  int tid = threadIdx.x, lane = tid & 63, wid = tid >> 6;  // 4 waves 2x2
  int wm = wid >> 1, wn = wid & 1;
  int lr = lane & 15, lq = lane >> 4;
  __shared__ char smem[33792];         // GEMM 32768; repack 64*132*4=33792
  char* Ab = smem;
  char* Bb = smem + 16384;

  int l8 = lane >> 3, kgl = lane & 7;
  int xorg = (kgl ^ l8) * 8;
  const ushort* srcA[4]; const ushort* srcB[4];
#pragma unroll
  for (int q = 0; q < 4; q++) {
    int r = (wid * 4 + q) * 8 + l8;
    int m = mt * 128 + r;
    srcA[q] = y2p + (size_t)m * MIDC + xorg;
    int n = nt * 128 + r;
    srcB[q] = W3b + (size_t)n * MIDC + xorg;
  }
  f32x4 acc[4][4] = {};

  for (int kt = 0; kt < 4; kt++) {
    int d = kt * 64;
#pragma unroll
    for (int q = 0; q < 4; q++) GLOAD16(srcA[q] + d, Ab + (wid * 4 + q) * 1024);
#pragma unroll
    for (int q = 0; q < 4; q++) GLOAD16(srcB[q] + d, Bb + (wid * 4 + q) * 1024);
    __syncthreads();
#pragma unroll
    for (int kk = 0; kk < 2; kk++) {
      int kg = kk * 4 + lq;
      short8 af[4], bf[4];
#pragma unroll
      for (int i = 0; i < 4; i++) {
        int row = wm * 64 + i * 16 + lr;
        af[i] = *(const short8*)(Ab + row * 128 + ((kg ^ (row & 7)) << 4));
      }
#pragma unroll
      for (int j = 0; j < 4; j++) {
        int rn = wn * 64 + j * 16 + lr;
        bf[j] = *(const short8*)(Bb + rn * 128 + ((kg ^ (rn & 7)) << 4));
      }
#pragma unroll
      for (int i = 0; i < 4; i++)
#pragma unroll
        for (int j = 0; j < 4; j++)
          acc[i][j] = __builtin_amdgcn_mfma_f32_16x16x32_bf16(af[i], bf[j], acc[i][j], 0, 0, 0);
    }
    __syncthreads();
  }

  // stats (all m valid: 392*128 == 50176)
#pragma unroll
  for (int j = 0; j < 4; j++) {
    float s = 0.f, q = 0.f;
#pragma unroll
    for (int i = 0; i < 4; i++)
#pragma unroll
      for (int r = 0; r < 4; r++) { float v = acc[i][j][r]; s += v; q += v * v; }
    s += __shfl_xor(s, 16); s += __shfl_xor(s, 32);
    q += __shfl_xor(q, 16); q += __shfl_xor(q, 32);
    if (lane < 16) {
      int n = nt * 128 + wn * 64 + j * 16 + lane;
      atomicAdd(&sum3[n], s); atomicAdd(&sq3[n], q);
    }
  }

  // z bf16 NCHW via LDS repack; copy-out writes 256B contiguous per 16 lanes
  float* ldsf = (float*)smem;          // [64][132]
  int m0t = mt * 128;
  for (int h = 0; h < 2; h++) {
    __syncthreads();
    if (wn == h) {
#pragma unroll
      for (int i = 0; i < 4; i++)
#pragma unroll
        for (int j = 0; j < 4; j++) {
          int nc = j * 16 + lr;
#pragma unroll
          for (int r = 0; r < 4; r++) {
            int m = wm * 64 + i * 16 + lq * 4 + r;
            ldsf[nc * 132 + m] = acc[i][j][r];
          }
        }
    }
    __syncthreads();
    int c0 = nt * 128 + h * 64;
    int l = tid & 15;
    int m = m0t + l * 8;                 // 784%8==0: same b for all 8
    int b = m / HWD, hw = m % HWD;
#pragma unroll
    for (int pass = 0; pass < 4; pass++) {
      int row = pass * 16 + (tid >> 4);
      const float* src = &ldsf[row * 132 + l * 8];
      uint4 pv;
      pv.x = pack2(src[0], src[1]); pv.y = pack2(src[2], src[3]);
      pv.z = pack2(src[4], src[5]); pv.w = pack2(src[6], src[7]);
      *(uint4*)(zbn + ((size_t)(b * COUTC + c0 + row)) * HWD + hw) = pv;
    }
  }
}

// ---------------- final: out = relu(bn3(zbn) + x), fully linear ------------
__global__ __launch_bounds__(256) void k_final(
    const ushort* __restrict__ zbn, const float* __restrict__ x,
    const float* __restrict__ s3, const float* __restrict__ t3,
    float* __restrict__ outp) {
  int stride = gridDim.x * blockDim.x;
  int total = (NB * COUTC * HWD) / 8;
  for (int i = blockIdx.x * blockDim.x + threadIdx.x; i < total; i += stride) {
    size_t e0 = (size_t)i * 8;
    int c = (int)((e0 / HWD) & (COUTC - 1));   // 784%8==0: same c for all 8
    float s = s3[c], tt = t3[c];
    uint4 zr = *(const uint4*)(zbn + e0);
    ushort* zw = (ushort*)&zr;
    float4 x0 = *(const float4*)(x + e0);
    float4 x1 = *(const float4*)(x + e0 + 4);
    float4 o0, o1;
    o0.x = fmaxf(fmaf(bf2f(zw[0]), s, tt) + x0.x, 0.f);
    o0.y = fmaxf(fmaf(bf2f(zw[1]), s, tt) + x0.y, 0.f);
    o0.z = fmaxf(fmaf(bf2f(zw[2]), s, tt) + x0.z, 0.f);
    o0.w = fmaxf(fmaf(bf2f(zw[3]), s, tt) + x0.w, 0.f);
    o1.x = fmaxf(fmaf(bf2f(zw[4]), s, tt) + x1.x, 0.f);
    o1.y = fmaxf(fmaf(bf2f(zw[5]), s, tt) + x1.y, 0.f);
    o1.z = fmaxf(fmaf(bf2f(zw[6]), s, tt) + x1.z, 0.f);
    o1.w = fmaxf(fmaf(bf2f(zw[7]), s, tt) + x1.w, 0.f);
    *(float4*)(outp + e0) = o0;
    *(float4*)(outp + e0 + 4) = o1;
  }
}

extern "C" void kernel_launch(void* const* d_in, const int* in_sizes, int n_in,
                              void* d_out, int out_size, void* d_ws, size_t ws_size,
                              hipStream_t stream) {
  const float* x    = (const float*)d_in[0];
  const float* emb  = (const float*)d_in[1];
  const float* wg1  = (const float*)d_in[2];
  const float* bg1  = (const float*)d_in[3];
  const float* wg2  = (const float*)d_in[4];
  const float* bg2  = (const float*)d_in[5];
  const float* c1w  = (const float*)d_in[6];
  const float* bn1g = (const float*)d_in[7];
  const float* bn1b = (const float*)d_in[8];
  const float* c2w  = (const float*)d_in[9];
  const float* bn2g = (const float*)d_in[10];
  const float* bn2b = (const float*)d_in[11];
  const float* c3w  = (const float*)d_in[12];
  const float* bn3g = (const float*)d_in[13];
  const float* bn3b = (const float*)d_in[14];

  float* out = (float*)d_out;
  char* ws = (char*)d_ws;
  ushort* y1  = (ushort*)(ws + OFF_Y1);
  ushort* y2p = (ushort*)(ws + OFF_Y1);   // reuses y1 region (y1 dead after k_bnrelu)
  ushort* y2  = (ushort*)(ws + OFF_Y2);
  ushort* W1b = (ushort*)(ws + OFF_W1);
  ushort* W3b = (ushort*)(ws + OFF_W3);
  ushort* W2r = (ushort*)(ws + OFF_W2R);
  float* stat = (float*)(ws + OFF_STAT);
  float* par  = (float*)(ws + OFF_PAR);
  ushort* zbn = (ushort*)(ws + OFF_ZB);

  float* sum1 = stat;        float* sq1 = stat + 256;
  float* sum2 = stat + 512;  float* sq2 = stat + 768;
  float* sum3 = stat + 1024; float* sq3 = stat + 2048;
  float* s1 = par;        float* t1 = par + 256;
  float* s2 = par + 512;  float* t2 = par + 768;
  float* s3 = par + 1024; float* t3 = par + 2048;

  // d_out aliasing: xcl bf16 [0..102.76MB) dead after conv1; y1p bf16
  // [102.76..132.25MB) dead after conv2; out f32 written by k_final last.
  ushort* xcl = (ushort*)out;
  ushort* y1p = (ushort*)(out + 25690112);
  float* out_tail = out + 51380224;

  hipMemsetAsync(stat, 0, 3072 * sizeof(float), stream);
  k_gates<<<dim3(64, 2), 256, 0, stream>>>(emb, wg1, bg1, wg2, bg2, out_tail);
  k_repack<<<2048, 256, 0, stream>>>(c1w, c2w, c3w, W1b, W2r, W3b);
  k_xpose<<<dim3(13, 16, 64), 256, 0, stream>>>(x, xcl);
  k_conv1<<<784, 256, 0, stream>>>(xcl, W1b, out_tail, y1, sum1, sq1);
  k_bnpar<<<1, 256, 0, stream>>>(stat, bn1g, bn1b, s1, t1, 256);
  k_bnrelu<<<7200, 256, 0, stream>>>(y1, s1, t1, y1p);
  k_conv2<<<784, 256, 0, stream>>>(y1p, W2r, out_tail + 16384, y2, sum2, sq2);
  k_bnpar<<<1, 256, 0, stream>>>(stat + 512, bn2g, bn2b, s2, t2, 256);
  k_bnrelu2<<<6272, 256, 0, stream>>>(y2, s2, t2, y2p);
  k_conv3<<<3136, 256, 0, stream>>>(y2p, W3b, zbn, sum3, sq3);
  k_bnpar<<<4, 256, 0, stream>>>(stat + 1024, bn3g, bn3b, s3, t3, 1024);
  k_final<<<2048, 256, 0, stream>>>(zbn, x, s3, t3, out);
}

// Round 11
// 378.637 us; speedup vs baseline: 1.0567x; 1.0279x over previous
//
#include <hip/hip_runtime.h>
#include <stdint.h>

#define NB 64
#define CINC 1024
#define HWD 784
#define MIDC 256
#define COUTC 1024
#define EMBD 64

typedef __attribute__((ext_vector_type(8))) short short8;
typedef __attribute__((ext_vector_type(4))) float f32x4;

#define GLOAD16(gp, lp)                                                     \
  __builtin_amdgcn_global_load_lds(                                         \
      (const __attribute__((address_space(1))) void*)(gp),                  \
      (__attribute__((address_space(3))) void*)(lp), 16, 0, 0)

__device__ __forceinline__ ushort f2bf(float f) {
  union { float f; uint32_t u; } v; v.f = f;
  uint32_t r = v.u + 0x7fffu + ((v.u >> 16) & 1u);
  return (ushort)(r >> 16);
}
__device__ __forceinline__ float bf2f(ushort b) {
  union { uint32_t u; float f; } v; v.u = ((uint32_t)b) << 16;
  return v.f;
}
__device__ __forceinline__ uint32_t pack2(float a, float b) {
  return (uint32_t)f2bf(a) | ((uint32_t)f2bf(b) << 16);
}

// ---------------- workspace layout (bytes) ----------------
static const size_t OFF_Y1   = 0;            // y1, later reused as y2p
static const size_t OFF_Y2   = 25690112;
static const size_t OFF_W1   = 51380224;
static const size_t OFF_W3   = 51904512;
static const size_t OFF_W2R  = 52428800;
static const size_t OFF_STAT = 53608448;     // 3072 floats
static const size_t OFF_ZB   = 58720256;     // z bf16 NCHW = 102760448 B

// ---------------- setup: gates + weight repack + stat zero ----------------
__global__ __launch_bounds__(256) void k_setup(
    const float* __restrict__ emb, const float* __restrict__ wg1,
    const float* __restrict__ bg1, const float* __restrict__ wg2,
    const float* __restrict__ bg2, float* __restrict__ out_tail,
    const float* __restrict__ w1, const float* __restrict__ w2,
    const float* __restrict__ w3, ushort* __restrict__ W1b,
    ushort* __restrict__ W2r, ushort* __restrict__ W3b,
    float* __restrict__ stat) {
  int bid = blockIdx.x;
  if (bid < 128) {
    int b = bid >> 1, which = bid & 1, n = threadIdx.x;
    const float* w = which ? wg2 : wg1;
    const float* bias = which ? bg2 : bg1;
    __shared__ float se[EMBD];
    if (n < EMBD) se[n] = emb[b * EMBD + n];
    __syncthreads();
    float acc = bias[n];
#pragma unroll 8
    for (int e = 0; e < EMBD; e++) acc += se[e] * w[e * MIDC + n];
    out_tail[which * (NB * MIDC) + b * MIDC + n] = fmaxf(acc, 0.f);
  } else {
    int rb = bid - 128;
    int j0 = rb * 256 + threadIdx.x;
    if (j0 < 3072) stat[j0] = 0.f;
    int total = 262144 + 262144 + 589824;
    for (int i = j0; i < total; i += 2048 * 256) {
      if (i < 262144) W1b[i] = f2bf(w1[i]);
      else if (i < 524288) W3b[i - 262144] = f2bf(w3[i - 262144]);
      else {
        int j = i - 524288;               // tap*65536 + n*256 + c
        int tap = j >> 16, n = (j >> 8) & 255, c = j & 255;
        W2r[j] = f2bf(w2[(n * 256 + c) * 9 + tap]);
      }
    }
  }
}

// ---------------- x (NCHW f32) -> xcl [m][c] bf16 ----------------
__global__ __launch_bounds__(256) void k_xpose(const float* __restrict__ x,
                                               ushort* __restrict__ xcl) {
  int mt = blockIdx.x, ct = blockIdx.y, b = blockIdx.z;
  __shared__ float tile[64][68];
  int t = threadIdx.x;
  int m0 = mt * 64, c0 = ct * 64;
  {
    int cc = t >> 2, mc = (t & 3) << 4;
    if (m0 + mc < HWD) {
      const float* src = x + ((size_t)b * CINC + c0 + cc) * HWD + m0 + mc;
#pragma unroll
      for (int e = 0; e < 4; e++) {
        float4 q = ((const float4*)src)[e];
        int mm = mc + e * 4;
        tile[mm][cc] = q.x; tile[mm + 1][cc] = q.y;
        tile[mm + 2][cc] = q.z; tile[mm + 3][cc] = q.w;
      }
    }
  }
  __syncthreads();
  {
    int m = t >> 2, cc = (t & 3) << 4;
    int mi = m0 + m;
    if (mi < HWD) {
      float* row = tile[m];
      uint32_t w[8];
#pragma unroll
      for (int e = 0; e < 8; e++) w[e] = pack2(row[cc + 2 * e], row[cc + 2 * e + 1]);
      uint4 p0, p1;
      p0.x = w[0]; p0.y = w[1]; p0.z = w[2]; p0.w = w[3];
      p1.x = w[4]; p1.y = w[5]; p1.z = w[6]; p1.w = w[7];
      uint4* dst = (uint4*)(xcl + ((size_t)b * HWD + mi) * CINC + c0 + cc);
      dst[0] = p0; dst[1] = p1;
    }
  }
}

// ---------------- conv1 1x1 (m97-style): M=50176 x N=256(2 nt) x K=1024 ----
__global__ __launch_bounds__(256, 3) void k_conv1(
    const ushort* __restrict__ xcl, const ushort* __restrict__ W1b,
    const float* __restrict__ g1, ushort* __restrict__ y1,
    float* __restrict__ sum1, float* __restrict__ sq1) {
  int bid = (blockIdx.x & 7) * 98 + (blockIdx.x >> 3);   // XCD chunked swizzle
  int mt = bid >> 1, nt = bid & 1;
  int tid = threadIdx.x, lane = tid & 63, wid = tid >> 6;  // 4 waves 2x2
  int wm = wid >> 1, wn = wid & 1;
  int lr = lane & 15, lq = lane >> 4;
  __shared__ char smem[32768];
  char* Ab = smem;            // 128 rows x 128B
  char* Bb = smem + 16384;    // 128 rows x 128B

  int l8 = lane >> 3, kgl = lane & 7;
  int xorg = (kgl ^ l8) * 8;  // element offset of swizzled granule
  const ushort* srcA[4]; const ushort* srcB[4];
#pragma unroll
  for (int q = 0; q < 4; q++) {
    int r = (wid * 4 + q) * 8 + l8;
    int m = mt * 128 + r;
    srcA[q] = xcl + (size_t)m * CINC + xorg;
    int n = nt * 128 + r;
    srcB[q] = W1b + (size_t)n * CINC + xorg;
  }
  f32x4 acc[4][4] = {};

  for (int kt = 0; kt < 16; kt++) {
    int d = kt * 64;
#pragma unroll
    for (int q = 0; q < 4; q++) GLOAD16(srcA[q] + d, Ab + (wid * 4 + q) * 1024);
#pragma unroll
    for (int q = 0; q < 4; q++) GLOAD16(srcB[q] + d, Bb + (wid * 4 + q) * 1024);
    __syncthreads();
#pragma unroll
    for (int kk = 0; kk < 2; kk++) {
      int kg = kk * 4 + lq;
      short8 af[4], bf[4];
#pragma unroll
      for (int i = 0; i < 4; i++) {
        int row = wm * 64 + i * 16 + lr;
        af[i] = *(const short8*)(Ab + row * 128 + ((kg ^ (row & 7)) << 4));
      }
#pragma unroll
      for (int j = 0; j < 4; j++) {
        int rn = wn * 64 + j * 16 + lr;
        bf[j] = *(const short8*)(Bb + rn * 128 + ((kg ^ (rn & 7)) << 4));
      }
#pragma unroll
      for (int i = 0; i < 4; i++)
#pragma unroll
        for (int j = 0; j < 4; j++)
          acc[i][j] = __builtin_amdgcn_mfma_f32_16x16x32_bf16(af[i], bf[j], acc[i][j], 0, 0, 0);
    }
    __syncthreads();
  }

  // epilogue: gate (b = m/784, at most 2 distinct b per tile), stats, store
  int m0t = mt * 128;
  int b0 = m0t / HWD;
  int b1 = b0 + 1; if (b1 > NB - 1) b1 = NB - 1;
  int thr = (b0 + 1) * HWD;
  float gv0[4], gv1[4];
#pragma unroll
  for (int j = 0; j < 4; j++) {
    int n = nt * 128 + wn * 64 + j * 16 + lr;
    gv0[j] = g1[b0 * MIDC + n];
    gv1[j] = g1[b1 * MIDC + n];
  }
#pragma unroll
  for (int i = 0; i < 4; i++) {
    int mlb = m0t + wm * 64 + i * 16 + lq * 4;
#pragma unroll
    for (int j = 0; j < 4; j++)
#pragma unroll
      for (int r = 0; r < 4; r++)
        acc[i][j][r] *= ((mlb + r) < thr) ? gv0[j] : gv1[j];
  }
#pragma unroll
  for (int j = 0; j < 4; j++) {
    float s = 0.f, q = 0.f;
#pragma unroll
    for (int i = 0; i < 4; i++)
#pragma unroll
      for (int r = 0; r < 4; r++) { float v = acc[i][j][r]; s += v; q += v * v; }
    s += __shfl_xor(s, 16); s += __shfl_xor(s, 32);
    q += __shfl_xor(q, 16); q += __shfl_xor(q, 32);
    if (lane < 16) {
      int n = nt * 128 + wn * 64 + j * 16 + lane;
      atomicAdd(&sum1[n], s); atomicAdd(&sq1[n], q);
    }
  }
#pragma unroll
  for (int i = 0; i < 4; i++)
#pragma unroll
    for (int r = 0; r < 4; r++) {
      int m = m0t + wm * 64 + i * 16 + lq * 4 + r;
      ushort* dst = y1 + (size_t)m * MIDC + nt * 128 + wn * 64 + lr;
#pragma unroll
      for (int j = 0; j < 4; j++) dst[j * 16] = f2bf(acc[i][j][r]);
    }
}

// ---------------- bn1+relu prepass (bnpar inlined): y1 -> y1p padded -------
__global__ __launch_bounds__(256) void k_bnrelu(
    const ushort* __restrict__ y1, const float* __restrict__ st,
    const float* __restrict__ gamma, const float* __restrict__ beta,
    ushort* __restrict__ y1p) {
  __shared__ float sS[MIDC], sT[MIDC];
  int t = threadIdx.x;
  {
    const float cnt = 50176.f;
    float m = st[t] / cnt;
    float v = st[MIDC + t] / cnt - m * m;
    float s = gamma[t] * rsqrtf(v + 1e-5f);
    sS[t] = s; sT[t] = beta[t] - m * s;
  }
  __syncthreads();
  int pl = t >> 5, ch = (t & 31) * 8;
  int pos = blockIdx.x * 8 + pl;          // 0..57599
  int b = pos / 900, pp = pos % 900;
  int pr = pp / 30, pc = pp % 30;
  uint4 ov = {0u, 0u, 0u, 0u};
  if (pr > 0 && pr < 29 && pc > 0 && pc < 29) {
    uint4 raw = *(const uint4*)(y1 + ((size_t)b * HWD + (pr - 1) * 28 + (pc - 1)) * MIDC + ch);
    ushort* rw = (ushort*)&raw; ushort* ow = (ushort*)&ov;
#pragma unroll
    for (int e = 0; e < 8; e++) {
      float f = bf2f(rw[e]) * sS[ch + e] + sT[ch + e];
      ow[e] = f2bf(fmaxf(f, 0.f));
    }
  }
  *(uint4*)(y1p + (size_t)pos * MIDC + ch) = ov;
}

// ---------------- bn2+relu prepass (bnpar inlined): y2 -> y2p --------------
__global__ __launch_bounds__(256) void k_bnrelu2(
    const ushort* __restrict__ y2, const float* __restrict__ st,
    const float* __restrict__ gamma, const float* __restrict__ beta,
    ushort* __restrict__ y2p) {
  __shared__ float sS[MIDC], sT[MIDC];
  int t = threadIdx.x;
  {
    const float cnt = 50176.f;
    float m = st[t] / cnt;
    float v = st[MIDC + t] / cnt - m * m;
    float s = gamma[t] * rsqrtf(v + 1e-5f);
    sS[t] = s; sT[t] = beta[t] - m * s;
  }
  __syncthreads();
  int pl = t >> 5, ch = (t & 31) * 8;
  size_t pos = (size_t)blockIdx.x * 8 + pl;   // 0..50175
  uint4 raw = *(const uint4*)(y2 + pos * MIDC + ch);
  uint4 ov;
  ushort* rw = (ushort*)&raw; ushort* ow = (ushort*)&ov;
#pragma unroll
  for (int e = 0; e < 8; e++) {
    float f = bf2f(rw[e]) * sS[ch + e] + sT[ch + e];
    ow[e] = f2bf(fmaxf(f, 0.f));
  }
  *(uint4*)(y2p + pos * MIDC + ch) = ov;
}

// ---------------- conv2 3x3 (m97-style implicit GEMM over padded y1p) -------
__global__ __launch_bounds__(256, 3) void k_conv2(
    const ushort* __restrict__ y1p, const ushort* __restrict__ W2r,
    const float* __restrict__ g2, ushort* __restrict__ y2,
    float* __restrict__ sum2, float* __restrict__ sq2) {
  int bid = (blockIdx.x & 7) * 98 + (blockIdx.x >> 3);   // XCD chunked swizzle
  int mt = bid >> 1, nt = bid & 1;
  int tid = threadIdx.x, lane = tid & 63, wid = tid >> 6;  // 4 waves 2x2
  int wm = wid >> 1, wn = wid & 1;
  int lr = lane & 15, lq = lane >> 4;
  __shared__ char smem[32768];
  char* Ab = smem;            // 128 rows x 128B
  char* Bb = smem + 16384;    // 128 rows x 128B

  int l8 = lane >> 3, kgl = lane & 7;
  int xorg = (kgl ^ l8) * 8;
  const ushort* srcA[4]; const ushort* srcB[4];
#pragma unroll
  for (int q = 0; q < 4; q++) {
    int r = (wid * 4 + q) * 8 + l8;
    int m = mt * 128 + r;
    int b = m / HWD, rem = m % HWD;
    int h = rem / 28, w = rem % 28;
    srcA[q] = y1p + ((size_t)b * 900 + (h + 1) * 30 + (w + 1)) * MIDC + xorg;
    int n = nt * 128 + r;
    srcB[q] = W2r + (size_t)n * MIDC + xorg;
  }
  f32x4 acc[4][4] = {};

  for (int kt = 0; kt < 36; kt++) {
    int tap = kt >> 2, cq = kt & 3;
    int dy = tap / 3, dx = tap % 3;
    int dA = ((dy - 1) * 30 + (dx - 1)) * MIDC + cq * 64;
    int dB = tap * 65536 + cq * 64;
#pragma unroll
    for (int q = 0; q < 4; q++) GLOAD16(srcA[q] + dA, Ab + (wid * 4 + q) * 1024);
#pragma unroll
    for (int q = 0; q < 4; q++) GLOAD16(srcB[q] + dB, Bb + (wid * 4 + q) * 1024);
    __syncthreads();
#pragma unroll
    for (int kk = 0; kk < 2; kk++) {
      int kg = kk * 4 + lq;
      short8 af[4], bf[4];
#pragma unroll
      for (int i = 0; i < 4; i++) {
        int row = wm * 64 + i * 16 + lr;
        af[i] = *(const short8*)(Ab + row * 128 + ((kg ^ (row & 7)) << 4));
      }
#pragma unroll
      for (int j = 0; j < 4; j++) {
        int rn = wn * 64 + j * 16 + lr;
        bf[j] = *(const short8*)(Bb + rn * 128 + ((kg ^ (rn & 7)) << 4));
      }
#pragma unroll
      for (int i = 0; i < 4; i++)
#pragma unroll
        for (int j = 0; j < 4; j++)
          acc[i][j] = __builtin_amdgcn_mfma_f32_16x16x32_bf16(af[i], bf[j], acc[i][j], 0, 0, 0);
    }
    __syncthreads();
  }

  // epilogue
  int m0t = mt * 128;
  int b0 = m0t / HWD;
  int b1 = b0 + 1; if (b1 > NB - 1) b1 = NB - 1;
  int thr = (b0 + 1) * HWD;
  float gv0[4], gv1[4];
#pragma unroll
  for (int j = 0; j < 4; j++) {
    int n = nt * 128 + wn * 64 + j * 16 + lr;
    gv0[j] = g2[b0 * MIDC + n];
    gv1[j] = g2[b1 * MIDC + n];
  }
#pragma unroll
  for (int i = 0; i < 4; i++) {
    int mlb = m0t + wm * 64 + i * 16 + lq * 4;
#pragma unroll
    for (int j = 0; j < 4; j++)
#pragma unroll
      for (int r = 0; r < 4; r++)
        acc[i][j][r] *= ((mlb + r) < thr) ? gv0[j] : gv1[j];
  }
#pragma unroll
  for (int j = 0; j < 4; j++) {
    float s = 0.f, q = 0.f;
#pragma unroll
    for (int i = 0; i < 4; i++)
#pragma unroll
      for (int r = 0; r < 4; r++) { float v = acc[i][j][r]; s += v; q += v * v; }
    s += __shfl_xor(s, 16); s += __shfl_xor(s, 32);
    q += __shfl_xor(q, 16); q += __shfl_xor(q, 32);
    if (lane < 16) {
      int n = nt * 128 + wn * 64 + j * 16 + lane;
      atomicAdd(&sum2[n], s); atomicAdd(&sq2[n], q);
    }
  }
#pragma unroll
  for (int i = 0; i < 4; i++)
#pragma unroll
    for (int r = 0; r < 4; r++) {
      int m = m0t + wm * 64 + i * 16 + lq * 4 + r;
      ushort* dst = y2 + (size_t)m * MIDC + nt * 128 + wn * 64 + lr;
#pragma unroll
      for (int j = 0; j < 4; j++) dst[j * 16] = f2bf(acc[i][j][r]);
    }
}

// ---------------- conv3 1x1 (m97-style): M=50176 x N=1024(8 nt) x K=256 -----
__global__ __launch_bounds__(256, 3) void k_conv3(
    const ushort* __restrict__ y2p, const ushort* __restrict__ W3b,
    ushort* __restrict__ zbn, float* __restrict__ sum3, float* __restrict__ sq3) {
  int bid = (blockIdx.x & 7) * 392 + (blockIdx.x >> 3);  // XCD chunked swizzle
  int mt = bid >> 3, nt = bid & 7;
  int tid = threadIdx.x, lane = tid & 63, wid = tid >> 6;  // 4 waves 2x2
  int wm = wid >> 1, wn = wid & 1;
  int lr = lane & 15, lq = lane >> 4;
  __shared__ char smem[33792];         // GEMM 32768; repack 64*132*4=33792
  char* Ab = smem;
  char* Bb = smem + 16384;

  int l8 = lane >> 3, kgl = lane & 7;
  int xorg = (kgl ^ l8) * 8;
  const ushort* srcA[4]; const ushort* srcB[4];
#pragma unroll
  for (int q = 0; q < 4; q++) {
    int r = (wid * 4 + q) * 8 + l8;
    int m = mt * 128 + r;
    srcA[q] = y2p + (size_t)m * MIDC + xorg;
    int n = nt * 128 + r;
    srcB[q] = W3b + (size_t)n * MIDC + xorg;
  }
  f32x4 acc[4][4] = {};

  for (int kt = 0; kt < 4; kt++) {
    int d = kt * 64;
#pragma unroll
    for (int q = 0; q < 4; q++) GLOAD16(srcA[q] + d, Ab + (wid * 4 + q) * 1024);
#pragma unroll
    for (int q = 0; q < 4; q++) GLOAD16(srcB[q] + d, Bb + (wid * 4 + q) * 1024);
    __syncthreads();
#pragma unroll
    for (int kk = 0; kk < 2; kk++) {
      int kg = kk * 4 + lq;
      short8 af[4], bf[4];
#pragma unroll
      for (int i = 0; i < 4; i++) {
        int row = wm * 64 + i * 16 + lr;
        af[i] = *(const short8*)(Ab + row * 128 + ((kg ^ (row & 7)) << 4));
      }
#pragma unroll
      for (int j = 0; j < 4; j++) {
        int rn = wn * 64 + j * 16 + lr;
        bf[j] = *(const short8*)(Bb + rn * 128 + ((kg ^ (rn & 7)) << 4));
      }
#pragma unroll
      for (int i = 0; i < 4; i++)
#pragma unroll
        for (int j = 0; j < 4; j++)
          acc[i][j] = __builtin_amdgcn_mfma_f32_16x16x32_bf16(af[i], bf[j], acc[i][j], 0, 0, 0);
    }
    __syncthreads();
  }

  // stats (all m valid: 392*128 == 50176)
#pragma unroll
  for (int j = 0; j < 4; j++) {
    float s = 0.f, q = 0.f;
#pragma unroll
    for (int i = 0; i < 4; i++)
#pragma unroll
      for (int r = 0; r < 4; r++) { float v = acc[i][j][r]; s += v; q += v * v; }
    s += __shfl_xor(s, 16); s += __shfl_xor(s, 32);
    q += __shfl_xor(q, 16); q += __shfl_xor(q, 32);
    if (lane < 16) {
      int n = nt * 128 + wn * 64 + j * 16 + lane;
      atomicAdd(&sum3[n], s); atomicAdd(&sq3[n], q);
    }
  }

  // z bf16 NCHW via LDS repack; copy-out writes 256B contiguous per 16 lanes
  float* ldsf = (float*)smem;          // [64][132]
  int m0t = mt * 128;
  for (int h = 0; h < 2; h++) {
    __syncthreads();
    if (wn == h) {
#pragma unroll
      for (int i = 0; i < 4; i++)
#pragma unroll
        for (int j = 0; j < 4; j++) {
          int nc = j * 16 + lr;
#pragma unroll
          for (int r = 0; r < 4; r++) {
            int m = wm * 64 + i * 16 + lq * 4 + r;
            ldsf[nc * 132 + m] = acc[i][j][r];
          }
        }
    }
    __syncthreads();
    int c0 = nt * 128 + h * 64;
    int l = tid & 15;
    int m = m0t + l * 8;                 // 784%8==0: same b for all 8
    int b = m / HWD, hw = m % HWD;
#pragma unroll
    for (int pass = 0; pass < 4; pass++) {
      int row = pass * 16 + (tid >> 4);
      const float* src = &ldsf[row * 132 + l * 8];
      uint4 pv;
      pv.x = pack2(src[0], src[1]); pv.y = pack2(src[2], src[3]);
      pv.z = pack2(src[4], src[5]); pv.w = pack2(src[6], src[7]);
      *(uint4*)(zbn + ((size_t)(b * COUTC + c0 + row)) * HWD + hw) = pv;
    }
  }
}

// ---------------- final: out = relu(bn3(zbn) + x), bnpar3 inlined ----------
__global__ __launch_bounds__(256) void k_final(
    const ushort* __restrict__ zbn, const float* __restrict__ x,
    const float* __restrict__ sum3, const float* __restrict__ sq3,
    const float* __restrict__ gamma, const float* __restrict__ beta,
    float* __restrict__ outp) {
  int stride = gridDim.x * blockDim.x;
  int total = (NB * COUTC * HWD) / 8;
  for (int i = blockIdx.x * blockDim.x + threadIdx.x; i < total; i += stride) {
    size_t e0 = (size_t)i * 8;
    int c = (int)((e0 / HWD) & (COUTC - 1));   // 784%8==0: same c for all 8
    const float cnt = 50176.f;
    float mm = sum3[c] / cnt;
    float vv = sq3[c] / cnt - mm * mm;
    float s = gamma[c] * rsqrtf(vv + 1e-5f);
    float tt = beta[c] - mm * s;
    uint4 zr = *(const uint4*)(zbn + e0);
    ushort* zw = (ushort*)&zr;
    float4 x0 = *(const float4*)(x + e0);
    float4 x1 = *(const float4*)(x + e0 + 4);
    float4 o0, o1;
    o0.x = fmaxf(fmaf(bf2f(zw[0]), s, tt) + x0.x, 0.f);
    o0.y = fmaxf(fmaf(bf2f(zw[1]), s, tt) + x0.y, 0.f);
    o0.z = fmaxf(fmaf(bf2f(zw[2]), s, tt) + x0.z, 0.f);
    o0.w = fmaxf(fmaf(bf2f(zw[3]), s, tt) + x0.w, 0.f);
    o1.x = fmaxf(fmaf(bf2f(zw[4]), s, tt) + x1.x, 0.f);
    o1.y = fmaxf(fmaf(bf2f(zw[5]), s, tt) + x1.y, 0.f);
    o1.z = fmaxf(fmaf(bf2f(zw[6]), s, tt) + x1.z, 0.f);
    o1.w = fmaxf(fmaf(bf2f(zw[7]), s, tt) + x1.w, 0.f);
    *(float4*)(outp + e0) = o0;
    *(float4*)(outp + e0 + 4) = o1;
  }
}

extern "C" void kernel_launch(void* const* d_in, const int* in_sizes, int n_in,
                              void* d_out, int out_size, void* d_ws, size_t ws_size,
                              hipStream_t stream) {
  const float* x    = (const float*)d_in[0];
  const float* emb  = (const float*)d_in[1];
  const float* wg1  = (const float*)d_in[2];
  const float* bg1  = (const float*)d_in[3];
  const float* wg2  = (const float*)d_in[4];
  const float* bg2  = (const float*)d_in[5];
  const float* c1w  = (const float*)d_in[6];
  const float* bn1g = (const float*)d_in[7];
  const float* bn1b = (const float*)d_in[8];
  const float* c2w  = (const float*)d_in[9];
  const float* bn2g = (const float*)d_in[10];
  const float* bn2b = (const float*)d_in[11];
  const float* c3w  = (const float*)d_in[12];
  const float* bn3g = (const float*)d_in[13];
  const float* bn3b = (const float*)d_in[14];

  float* out = (float*)d_out;
  char* ws = (char*)d_ws;
  ushort* y1  = (ushort*)(ws + OFF_Y1);
  ushort* y2p = (ushort*)(ws + OFF_Y1);   // reuses y1 region (y1 dead after k_bnrelu)
  ushort* y2  = (ushort*)(ws + OFF_Y2);
  ushort* W1b = (ushort*)(ws + OFF_W1);
  ushort* W3b = (ushort*)(ws + OFF_W3);
  ushort* W2r = (ushort*)(ws + OFF_W2R);
  float* stat = (float*)(ws + OFF_STAT);
  ushort* zbn = (ushort*)(ws + OFF_ZB);

  float* sum1 = stat;        float* sq1 = stat + 256;
  float* sum2 = stat + 512;  float* sq2 = stat + 768;
  float* sum3 = stat + 1024; float* sq3 = stat + 2048;

  // d_out aliasing: xcl bf16 [0..102.76MB) dead after conv1; y1p bf16
  // [102.76..132.25MB) dead after conv2; out f32 written by k_final last.
  ushort* xcl = (ushort*)out;
  ushort* y1p = (ushort*)(out + 25690112);
  float* out_tail = out + 51380224;

  k_setup<<<2176, 256, 0, stream>>>(emb, wg1, bg1, wg2, bg2, out_tail,
                                    c1w, c2w, c3w, W1b, W2r, W3b, stat);
  k_xpose<<<dim3(13, 16, 64), 256, 0, stream>>>(x, xcl);
  k_conv1<<<784, 256, 0, stream>>>(xcl, W1b, out_tail, y1, sum1, sq1);
  k_bnrelu<<<7200, 256, 0, stream>>>(y1, stat, bn1g, bn1b, y1p);
  k_conv2<<<784, 256, 0, stream>>>(y1p, W2r, out_tail + 16384, y2, sum2, sq2);
  k_bnrelu2<<<6272, 256, 0, stream>>>(y2, stat + 512, bn2g, bn2b, y2p);
  k_conv3<<<3136, 256, 0, stream>>>(y2p, W3b, zbn, sum3, sq3);
  k_final<<<2048, 256, 0, stream>>>(zbn, x, sum3, sq3, bn3g, bn3b, out);
}